// Round 1
// baseline (1997.762 us; speedup 1.0000x reference)
//
#include <hip/hip_runtime.h>
#include <math.h>

#define B_   32
#define T_   1024
#define N_   77
#define D_   512
#define TD_  256
#define TE_  2048
#define H_   8
#define DH_  64

__device__ __forceinline__ float sigmoidf_fast(float x) {
    return 1.0f / (1.0f + __expf(-x));
}

// ---------------------------------------------------------------------------
// Row stats: mean + rstd per row (population var, eps=1e-5). One wave per row.
// ---------------------------------------------------------------------------
__global__ __launch_bounds__(256) void row_stats_kernel(
    const float* __restrict__ x, float* __restrict__ mu, float* __restrict__ rstd,
    int rows, int cols)
{
    int wave = blockIdx.x * 4 + (threadIdx.x >> 6);
    int lane = threadIdx.x & 63;
    if (wave >= rows) return;
    const float* row = x + (size_t)wave * cols;
    float s = 0.f, ss = 0.f;
    for (int c = lane; c < cols; c += 64) {
        float v = row[c];
        s += v; ss += v * v;
    }
    #pragma unroll
    for (int off = 32; off; off >>= 1) {
        s  += __shfl_xor(s, off);
        ss += __shfl_xor(ss, off);
    }
    if (lane == 0) {
        float m = s / cols;
        float var = ss / cols - m * m;
        mu[wave] = m;
        rstd[wave] = rsqrtf(var + 1e-5f);
    }
}

// ---------------------------------------------------------------------------
// Full LN (materialized) for xf: one wave per row of length cols.
// ---------------------------------------------------------------------------
__global__ __launch_bounds__(256) void ln_rows_kernel(
    const float* __restrict__ x, const float* __restrict__ w, const float* __restrict__ b,
    float* __restrict__ out, int rows, int cols)
{
    int wave = blockIdx.x * 4 + (threadIdx.x >> 6);
    int lane = threadIdx.x & 63;
    if (wave >= rows) return;
    const float* row = x + (size_t)wave * cols;
    float s = 0.f, ss = 0.f;
    for (int c = lane; c < cols; c += 64) {
        float v = row[c];
        s += v; ss += v * v;
    }
    #pragma unroll
    for (int off = 32; off; off >>= 1) {
        s  += __shfl_xor(s, off);
        ss += __shfl_xor(ss, off);
    }
    float m = s / cols;
    float var = ss / cols - m * m;
    float r = rsqrtf(var + 1e-5f);
    float* orow = out + (size_t)wave * cols;
    for (int c = lane; c < cols; c += 64) {
        orow[c] = (row[c] - m) * r * w[c] + b[c];
    }
}

// ---------------------------------------------------------------------------
// K/V projection: per (b,n) row. k = xfn@Wk.T + bk ; v = (xfn@Wv.T + bv)*tc[b]
// Block = 256 threads, each computes 2 outputs of k and 2 of v (dot-256).
// ---------------------------------------------------------------------------
__global__ __launch_bounds__(256) void kv_proj_kernel(
    const float* __restrict__ xfn,
    const float* __restrict__ Wk, const float* __restrict__ bk,
    const float* __restrict__ Wv, const float* __restrict__ bv,
    const int*   __restrict__ cond_type,
    float* __restrict__ kout, float* __restrict__ vout)
{
    int row = blockIdx.x;           // b*N + n
    int b = row / N_;
    __shared__ float ld[TD_];
    int t = threadIdx.x;
    ld[t] = xfn[(size_t)row * TD_ + t];
    __syncthreads();
    float tc = ((cond_type[b] % 10) > 0) ? 1.f : 0.f;
    #pragma unroll
    for (int oo = 0; oo < 2; oo++) {
        int o = t + oo * 256;
        const float* wkr = Wk + (size_t)o * TD_;
        const float* wvr = Wv + (size_t)o * TD_;
        float acck = 0.f, accv = 0.f;
        #pragma unroll 8
        for (int c = 0; c < TD_; c++) {
            float xv = ld[c];
            acck = fmaf(xv, wkr[c], acck);
            accv = fmaf(xv, wvr[c], accv);
        }
        kout[(size_t)row * D_ + o] = acck + bk[o];
        vout[(size_t)row * D_ + o] = (accv + bv[o]) * tc;
    }
}

// ---------------------------------------------------------------------------
// Tiled fp32 GEMM: C[M,NN] = transform(A)[M,K] @ W[NN,K]^T + bias (+ resid)
// MODE 0: A-transform = LayerNorm via precomputed (mu,rstd) + (lw,lb).  (Q proj)
// MODE 1: A-transform = silu( LN(y)*(1+scale[b,k]) + shift[b,k] ), C += x. (out proj)
// BM=BN=64, BK=16, 256 threads, 4x4 per thread.
// ---------------------------------------------------------------------------
template <int MODE>
__global__ __launch_bounds__(256) void gemm_kernel(
    const float* __restrict__ A, const float* __restrict__ W,
    const float* __restrict__ bias,
    const float* __restrict__ mu, const float* __restrict__ rstd,
    const float* __restrict__ lw, const float* __restrict__ lb,
    const float* __restrict__ e,      // [B, 2D] (MODE 1 only)
    const float* __restrict__ resid,  // x (MODE 1 only)
    float* __restrict__ C,
    int M, int NN, int K)
{
    const int tx = threadIdx.x & 15;       // 0..15 -> n
    const int ty = threadIdx.x >> 4;       // 0..15 -> m
    const int m0 = blockIdx.y * 64;
    const int n0 = blockIdx.x * 64;
    const int bb = m0 >> 10;               // batch index (T=1024, 64 | 1024)

    __shared__ float As[16][68];
    __shared__ float Ws[16][68];

    float acc[4][4] = {};

    // per-thread A-load rows are fixed across k-tiles: rows ty, ty+16, ty+32, ty+48
    float mur[4], rsr[4];
    #pragma unroll
    for (int p = 0; p < 4; p++) {
        int m = m0 + ty + p * 16;
        mur[p] = mu[m];
        rsr[p] = rstd[m];
    }

    for (int k0 = 0; k0 < K; k0 += 16) {
        int kk = k0 + tx;
        float lwk = lw[kk], lbk = lb[kk];
        float sck = 0.f, shk = 0.f;
        if (MODE == 1) {
            sck = e[(size_t)bb * 1024 + kk];
            shk = e[(size_t)bb * 1024 + 512 + kk];
        }
        #pragma unroll
        for (int p = 0; p < 4; p++) {
            int row = ty + p * 16;
            int m = m0 + row;
            float raw = A[(size_t)m * K + kk];
            float hn = (raw - mur[p]) * rsr[p] * lwk + lbk;
            float a;
            if (MODE == 0) {
                a = hn;
            } else {
                float h = hn * (1.f + sck) + shk;
                a = h * sigmoidf_fast(h);
            }
            As[tx][row] = a;
        }
        #pragma unroll
        for (int p = 0; p < 4; p++) {
            int nn = ty + p * 16;
            Ws[tx][nn] = W[(size_t)(n0 + nn) * K + kk];
        }
        __syncthreads();
        #pragma unroll
        for (int cc = 0; cc < 16; cc++) {
            float4 av = *(const float4*)&As[cc][ty * 4];
            float4 wv = *(const float4*)&Ws[cc][tx * 4];
            float a4[4] = {av.x, av.y, av.z, av.w};
            float w4[4] = {wv.x, wv.y, wv.z, wv.w};
            #pragma unroll
            for (int i = 0; i < 4; i++)
                #pragma unroll
                for (int j = 0; j < 4; j++)
                    acc[i][j] = fmaf(a4[i], w4[j], acc[i][j]);
        }
        __syncthreads();
    }

    #pragma unroll
    for (int i = 0; i < 4; i++) {
        int m = m0 + ty * 4 + i;
        #pragma unroll
        for (int j = 0; j < 4; j++) {
            int n = n0 + tx * 4 + j;
            float o = acc[i][j] + bias[n];
            if (MODE == 1) o += resid[(size_t)m * NN + n];
            C[(size_t)m * NN + n] = o;
        }
    }
}

// ---------------------------------------------------------------------------
// Cross-attention per (b,t) row, in-place on the q/y buffer.
// Block = 256 threads (4 waves); each wave handles 2 heads.
// Softmax bias is uniform over n per batch -> drops out; v already gated by tc.
// ---------------------------------------------------------------------------
__global__ __launch_bounds__(256) void attn_kernel(
    const float* __restrict__ kbuf, const float* __restrict__ vbuf,
    float* __restrict__ qy)
{
    int bt = blockIdx.x;        // b*T + t
    int b = bt >> 10;
    __shared__ float qs[D_];
    __shared__ float ps[H_][80];
    int t = threadIdx.x;
    qs[t]       = qy[(size_t)bt * D_ + t];
    qs[t + 256] = qy[(size_t)bt * D_ + t + 256];
    __syncthreads();

    int wave = t >> 6, lane = t & 63;
    const float* kb = kbuf + (size_t)b * N_ * D_;
    const float* vb = vbuf + (size_t)b * N_ * D_;

    #pragma unroll
    for (int hh = 0; hh < 2; hh++) {
        int h = wave * 2 + hh;
        const float* qh = qs + h * 64;
        float s0 = -1e30f, s1 = -1e30f;
        {
            const float* kr = kb + (size_t)lane * D_ + h * 64;
            float acc = 0.f;
            #pragma unroll 8
            for (int d = 0; d < 64; d++) acc = fmaf(qh[d], kr[d], acc);
            s0 = acc;   // n = lane (always < 77)
        }
        if (lane < N_ - 64) {
            const float* kr = kb + (size_t)(64 + lane) * D_ + h * 64;
            float acc = 0.f;
            #pragma unroll 8
            for (int d = 0; d < 64; d++) acc = fmaf(qh[d], kr[d], acc);
            s1 = acc;   // n = 64 + lane
        }
        float m = fmaxf(s0, s1);
        #pragma unroll
        for (int off = 32; off; off >>= 1) m = fmaxf(m, __shfl_xor(m, off));
        float e0 = __expf(s0 - m);
        float e1 = (lane < N_ - 64) ? __expf(s1 - m) : 0.f;
        float sum = e0 + e1;
        #pragma unroll
        for (int off = 32; off; off >>= 1) sum += __shfl_xor(sum, off);
        float inv = 1.f / sum;
        ps[h][lane] = e0 * inv;
        if (lane < N_ - 64) ps[h][64 + lane] = e1 * inv;
    }
    __syncthreads();

    #pragma unroll
    for (int hh = 0; hh < 2; hh++) {
        int h = wave * 2 + hh;
        float acc = 0.f;
        for (int n = 0; n < N_; n++)
            acc = fmaf(ps[h][n], vb[(size_t)n * D_ + h * 64 + lane], acc);
        qy[(size_t)bt * D_ + h * 64 + lane] = acc;
    }
}

// ---------------------------------------------------------------------------
// e = silu(emb) @ emb_w.T + emb_b   -> [B, 2D]. One wave per output.
// ---------------------------------------------------------------------------
__global__ __launch_bounds__(256) void emb_proj_kernel(
    const float* __restrict__ emb, const float* __restrict__ emb_w,
    const float* __restrict__ emb_b, float* __restrict__ e)
{
    int wid = blockIdx.x * 4 + (threadIdx.x >> 6);
    int lane = threadIdx.x & 63;
    if (wid >= B_ * 2 * D_) return;
    int b = wid >> 10;
    int oo = wid & 1023;
    const float* wr = emb_w + (size_t)oo * TE_;
    const float* er = emb + (size_t)b * TE_;
    float acc = 0.f;
    for (int i = lane; i < TE_; i += 64) {
        float x = er[i];
        float sx = x * sigmoidf_fast(x);
        acc = fmaf(sx, wr[i], acc);
    }
    #pragma unroll
    for (int off = 32; off; off >>= 1) acc += __shfl_xor(acc, off);
    if (lane == 0) e[wid] = acc + emb_b[oo];
}

// ---------------------------------------------------------------------------
extern "C" void kernel_launch(void* const* d_in, const int* in_sizes, int n_in,
                              void* d_out, int out_size, void* d_ws, size_t ws_size,
                              hipStream_t stream)
{
    const float* x       = (const float*)d_in[0];
    const float* xf      = (const float*)d_in[1];
    const float* emb     = (const float*)d_in[2];
    // d_in[3] = src_mask (unused by reference)
    const int*   cond    = (const int*)d_in[4];
    const float* norm_w  = (const float*)d_in[5];
    const float* norm_b  = (const float*)d_in[6];
    const float* tnorm_w = (const float*)d_in[7];
    const float* tnorm_b = (const float*)d_in[8];
    const float* Wq      = (const float*)d_in[9];
    const float* bq      = (const float*)d_in[10];
    const float* Wk      = (const float*)d_in[11];
    const float* bk      = (const float*)d_in[12];
    const float* Wv      = (const float*)d_in[13];
    const float* bv      = (const float*)d_in[14];
    const float* emb_w   = (const float*)d_in[15];
    const float* emb_b   = (const float*)d_in[16];
    const float* snorm_w = (const float*)d_in[17];
    const float* snorm_b = (const float*)d_in[18];
    const float* Wout    = (const float*)d_in[19];
    const float* bout    = (const float*)d_in[20];
    float* out = (float*)d_out;

    // workspace layout (floats)
    float* ws = (float*)d_ws;
    const size_t QY    = 0;                                  // 32768*512
    const size_t XFN   = QY    + (size_t)B_ * T_ * D_;       // 2464*256
    const size_t KBUF  = XFN   + (size_t)B_ * N_ * TD_;      // 2464*512
    const size_t VBUF  = KBUF  + (size_t)B_ * N_ * D_;       // 2464*512
    const size_t EBUF  = VBUF  + (size_t)B_ * N_ * D_;       // 32*1024
    const size_t XMU   = EBUF  + (size_t)B_ * 2 * D_;        // 32768
    const size_t XRS   = XMU   + (size_t)B_ * T_;
    const size_t YMU   = XRS   + (size_t)B_ * T_;
    const size_t YRS   = YMU   + (size_t)B_ * T_;

    float* qy   = ws + QY;
    float* xfn  = ws + XFN;
    float* kbuf = ws + KBUF;
    float* vbuf = ws + VBUF;
    float* ebuf = ws + EBUF;
    float* xmu  = ws + XMU;
    float* xrs  = ws + XRS;
    float* ymu  = ws + YMU;
    float* yrs  = ws + YRS;

    const int BT = B_ * T_;      // 32768
    const int BN = B_ * N_;      // 2464

    // 1. x row stats (for fused LN in Q-proj GEMM)
    row_stats_kernel<<<BT / 4, 256, 0, stream>>>(x, xmu, xrs, BT, D_);
    // 2. xf layernorm (materialized, small)
    ln_rows_kernel<<<(BN + 3) / 4, 256, 0, stream>>>(xf, tnorm_w, tnorm_b, xfn, BN, TD_);
    // 3. K/V projection (+ tc gating of v)
    kv_proj_kernel<<<BN, 256, 0, stream>>>(xfn, Wk, bk, Wv, bv, cond, kbuf, vbuf);
    // 4. Q projection: qy = LN(x) @ Wq^T + bq
    {
        dim3 grid(D_ / 64, BT / 64);
        gemm_kernel<0><<<grid, 256, 0, stream>>>(x, Wq, bq, xmu, xrs, norm_w, norm_b,
                                                 nullptr, nullptr, qy, BT, D_, D_);
    }
    // 5. attention (in-place q -> y)
    attn_kernel<<<BT, 256, 0, stream>>>(kbuf, vbuf, qy);
    // 6. e = silu(emb) @ emb_w^T + emb_b
    emb_proj_kernel<<<(B_ * 2 * D_) / 4, 256, 0, stream>>>(emb, emb_w, emb_b, ebuf);
    // 7. y row stats
    row_stats_kernel<<<BT / 4, 256, 0, stream>>>(qy, ymu, yrs, BT, D_);
    // 8. out = x + silu(LN(y)*(1+scale)+shift) @ Wout^T + bout
    {
        dim3 grid(D_ / 64, BT / 64);
        gemm_kernel<1><<<grid, 256, 0, stream>>>(qy, Wout, bout, ymu, yrs, snorm_w, snorm_b,
                                                 ebuf, x, out, BT, D_, D_);
    }
}

// Round 3
// 845.208 us; speedup vs baseline: 2.3636x; 2.3636x over previous
//
#include <hip/hip_runtime.h>
#include <math.h>

#define B_   32
#define T_   1024
#define N_   77
#define D_   512
#define TD_  256
#define TE_  2048
#define H_   8
#define DH_  64

typedef short bf16x8 __attribute__((ext_vector_type(8)));
typedef float f32x4  __attribute__((ext_vector_type(4)));

__device__ __forceinline__ float sigmoidf_fast(float x) {
    return 1.0f / (1.0f + __expf(-x));
}

// float -> bf16 bits, round-to-nearest-even
__device__ __forceinline__ unsigned short f2b(float f) {
    unsigned int u = __float_as_uint(f);
    unsigned int r = u + 0x7FFFu + ((u >> 16) & 1u);
    return (unsigned short)(r >> 16);
}

// ---------------------------------------------------------------------------
// Row stats: mean + rstd per row (population var, eps=1e-5). One wave per row.
// ---------------------------------------------------------------------------
__global__ __launch_bounds__(256) void row_stats_kernel(
    const float* __restrict__ x, float* __restrict__ mu, float* __restrict__ rstd,
    int rows, int cols)
{
    int wave = blockIdx.x * 4 + (threadIdx.x >> 6);
    int lane = threadIdx.x & 63;
    if (wave >= rows) return;
    const float* row = x + (size_t)wave * cols;
    float s = 0.f, ss = 0.f;
    for (int c = lane; c < cols; c += 64) {
        float v = row[c];
        s += v; ss += v * v;
    }
    #pragma unroll
    for (int off = 32; off; off >>= 1) {
        s  += __shfl_xor(s, off);
        ss += __shfl_xor(ss, off);
    }
    if (lane == 0) {
        float m = s / cols;
        float var = ss / cols - m * m;
        mu[wave] = m;
        rstd[wave] = rsqrtf(var + 1e-5f);
    }
}

// ---------------------------------------------------------------------------
// Full LN (materialized) for xf: one wave per row of length cols.
// ---------------------------------------------------------------------------
__global__ __launch_bounds__(256) void ln_rows_kernel(
    const float* __restrict__ x, const float* __restrict__ w, const float* __restrict__ b,
    float* __restrict__ out, int rows, int cols)
{
    int wave = blockIdx.x * 4 + (threadIdx.x >> 6);
    int lane = threadIdx.x & 63;
    if (wave >= rows) return;
    const float* row = x + (size_t)wave * cols;
    float s = 0.f, ss = 0.f;
    for (int c = lane; c < cols; c += 64) {
        float v = row[c];
        s += v; ss += v * v;
    }
    #pragma unroll
    for (int off = 32; off; off >>= 1) {
        s  += __shfl_xor(s, off);
        ss += __shfl_xor(ss, off);
    }
    float m = s / cols;
    float var = ss / cols - m * m;
    float r = rsqrtf(var + 1e-5f);
    float* orow = out + (size_t)wave * cols;
    for (int c = lane; c < cols; c += 64) {
        orow[c] = (row[c] - m) * r * w[c] + b[c];
    }
}

// ---------------------------------------------------------------------------
// Tiled fp32 GEMM: C[M,NN] = transform(A)[M,K] @ W[NN,K]^T + bias (+ extras)
// MODE 0: A-transform = LayerNorm via (mu,rstd,lw,lb).                (Q proj)
// MODE 1: A-transform = silu( LN(y)*(1+scale)+shift ), C += resid.  (out proj)
// MODE 2: A as-is.                                                    (K proj)
// MODE 3: A as-is; output scaled by tc[row/77].                       (V proj)
// BM=BN=64, BK=16, 256 threads, 4x4 per thread. M-boundary guarded.
// ---------------------------------------------------------------------------
template <int MODE>
__global__ __launch_bounds__(256) void gemm_kernel(
    const float* __restrict__ A, const float* __restrict__ W,
    const float* __restrict__ bias,
    const float* __restrict__ mu, const float* __restrict__ rstd,
    const float* __restrict__ lw, const float* __restrict__ lb,
    const float* __restrict__ e,      // [B, 2D] (MODE 1 only)
    const float* __restrict__ resid,  // x (MODE 1 only)
    const int*   __restrict__ cond,   // (MODE 3 only)
    float* __restrict__ C,
    int M, int NN, int K)
{
    const int tx = threadIdx.x & 15;       // 0..15 -> n
    const int ty = threadIdx.x >> 4;       // 0..15 -> m
    const int m0 = blockIdx.y * 64;
    const int n0 = blockIdx.x * 64;
    const int bb = m0 >> 10;               // batch index (valid for MODE 0/1)

    __shared__ float As[16][68];
    __shared__ float Ws[16][68];

    float acc[4][4] = {};

    float mur[4] = {0,0,0,0}, rsr[4] = {1,1,1,1};
    if (MODE == 0 || MODE == 1) {
        #pragma unroll
        for (int p = 0; p < 4; p++) {
            int m = m0 + ty + p * 16;
            int mc = m < M ? m : (M - 1);
            mur[p] = mu[mc];
            rsr[p] = rstd[mc];
        }
    }

    for (int k0 = 0; k0 < K; k0 += 16) {
        int kk = k0 + tx;
        float lwk = 1.f, lbk = 0.f, sck = 0.f, shk = 0.f;
        if (MODE == 0 || MODE == 1) { lwk = lw[kk]; lbk = lb[kk]; }
        if (MODE == 1) {
            sck = e[(size_t)bb * 1024 + kk];
            shk = e[(size_t)bb * 1024 + 512 + kk];
        }
        #pragma unroll
        for (int p = 0; p < 4; p++) {
            int row = ty + p * 16;
            int m = m0 + row;
            int mc = m < M ? m : (M - 1);
            float raw = A[(size_t)mc * K + kk];
            float a;
            if (MODE == 0) {
                a = (raw - mur[p]) * rsr[p] * lwk + lbk;
            } else if (MODE == 1) {
                float hn = (raw - mur[p]) * rsr[p] * lwk + lbk;
                float h = hn * (1.f + sck) + shk;
                a = h * sigmoidf_fast(h);
            } else {
                a = raw;
            }
            As[tx][row] = a;
        }
        #pragma unroll
        for (int p = 0; p < 4; p++) {
            int nn = ty + p * 16;
            Ws[tx][nn] = W[(size_t)(n0 + nn) * K + kk];
        }
        __syncthreads();
        #pragma unroll
        for (int cc = 0; cc < 16; cc++) {
            float4 av = *(const float4*)&As[cc][ty * 4];
            float4 wv = *(const float4*)&Ws[cc][tx * 4];
            float a4[4] = {av.x, av.y, av.z, av.w};
            float w4[4] = {wv.x, wv.y, wv.z, wv.w};
            #pragma unroll
            for (int i = 0; i < 4; i++)
                #pragma unroll
                for (int j = 0; j < 4; j++)
                    acc[i][j] = fmaf(a4[i], w4[j], acc[i][j]);
        }
        __syncthreads();
    }

    #pragma unroll
    for (int i = 0; i < 4; i++) {
        int m = m0 + ty * 4 + i;
        if (m >= M) continue;
        float rowscale = 1.f;
        if (MODE == 3) {
            int b3 = m / N_;
            rowscale = ((cond[b3] % 10) > 0) ? 1.f : 0.f;
        }
        #pragma unroll
        for (int j = 0; j < 4; j++) {
            int n = n0 + tx * 4 + j;
            float o = acc[i][j] + bias[n];
            if (MODE == 3) o *= rowscale;
            if (MODE == 1) o += resid[(size_t)m * NN + n];
            C[(size_t)m * NN + n] = o;
        }
    }
}

// ---------------------------------------------------------------------------
// MFMA bf16 cross-attention. Block = (t-tile=64, h, b), 256 threads (4 waves).
// Wave w owns the 16-row m-strip [w*16, w*16+16).
//   QK^T : D[t][n] = sum_d Q[t][d] K[n][d], n padded to 80
//   softmax in registers (shfl over 16-lane groups)
//   PV   : D[t][d] = sum_n P[t][n] V[n][d], n padded to 96 (P=0 pad)
// In-place qy update (each block touches only its own h-slice columns).
// ---------------------------------------------------------------------------
#define QS_OFF 0          // [64][72] bf16
#define KS_OFF 4608       // [80][72] bf16
#define VT_OFF 10368      // [64][104] bf16 (V transposed: row=d, col=n)
#define PS_OFF 17024      // [64][104] bf16 (P: row=t, col=n)
#define SMEM_SH 23680

__global__ __launch_bounds__(256) void attn_mfma_kernel(
    const float* __restrict__ kbuf, const float* __restrict__ vbuf,
    float* __restrict__ qy)
{
    __shared__ __align__(16) unsigned short smem[SMEM_SH];

    const int tid = threadIdx.x;
    const int t0 = blockIdx.x * 64;
    const int h  = blockIdx.y;
    const int b  = blockIdx.z;

    // ---- stage Q (64x64) ----
    const float* qbase = qy + ((size_t)(b * T_ + t0)) * D_ + h * 64;
    #pragma unroll
    for (int i = 0; i < 4; i++) {
        int idx = tid + i * 256;               // 1024 float4 slots
        int row = idx >> 4, c4 = idx & 15;
        float4 v = *(const float4*)(qbase + (size_t)row * D_ + c4 * 4);
        ushort4 o;
        o.x = f2b(v.x); o.y = f2b(v.y); o.z = f2b(v.z); o.w = f2b(v.w);
        *(ushort4*)&smem[QS_OFF + row * 72 + c4 * 4] = o;
    }
    // ---- stage K (77x64), zero rows 77..79 ----
    const float* kbase = kbuf + (size_t)(b * N_) * D_ + h * 64;
    #pragma unroll
    for (int i = 0; i < 5; i++) {
        int idx = tid + i * 256;
        if (idx < N_ * 16) {
            int row = idx >> 4, c4 = idx & 15;
            float4 v = *(const float4*)(kbase + (size_t)row * D_ + c4 * 4);
            ushort4 o;
            o.x = f2b(v.x); o.y = f2b(v.y); o.z = f2b(v.z); o.w = f2b(v.w);
            *(ushort4*)&smem[KS_OFF + row * 72 + c4 * 4] = o;
        }
    }
    if (tid < 48) {
        int row = N_ + tid / 16, c4 = tid & 15;
        ushort4 z = {0, 0, 0, 0};
        *(ushort4*)&smem[KS_OFF + row * 72 + c4 * 4] = z;
    }
    // ---- stage V transposed (VsT[d][n]), zero cols 77..95 ----
    const float* vbase = vbuf + (size_t)(b * N_) * D_ + h * 64;
    #pragma unroll
    for (int i = 0; i < 5; i++) {
        int idx = tid + i * 256;
        if (idx < N_ * 16) {
            int n = idx >> 4, c4 = idx & 15;
            float4 v = *(const float4*)(vbase + (size_t)n * D_ + c4 * 4);
            smem[VT_OFF + (c4 * 4 + 0) * 104 + n] = f2b(v.x);
            smem[VT_OFF + (c4 * 4 + 1) * 104 + n] = f2b(v.y);
            smem[VT_OFF + (c4 * 4 + 2) * 104 + n] = f2b(v.z);
            smem[VT_OFF + (c4 * 4 + 3) * 104 + n] = f2b(v.w);
        }
    }
    #pragma unroll
    for (int i = 0; i < 5; i++) {
        int idx = tid + i * 256;
        if (idx < 64 * 19) {
            int d = idx / 19, n = N_ + idx % 19;
            smem[VT_OFF + d * 104 + n] = 0;
        }
    }
    // ---- zero P pad cols 80..95 ----
    #pragma unroll
    for (int i = 0; i < 4; i++) {
        int idx = tid + i * 256;               // 1024 slots
        int row = idx >> 4, col = 80 + (idx & 15);
        smem[PS_OFF + row * 104 + col] = 0;
    }
    __syncthreads();

    const int lane = tid & 63;
    const int w    = tid >> 6;
    const int l15  = lane & 15;
    const int quad = lane >> 4;
    const int koff = quad * 8;
    const int mrow = w * 16 + l15;

    // ---- QK^T ----
    bf16x8 aq0 = *(const bf16x8*)&smem[QS_OFF + mrow * 72 + koff];
    bf16x8 aq1 = *(const bf16x8*)&smem[QS_OFF + mrow * 72 + 32 + koff];

    float s[5][4];
    #pragma unroll
    for (int nt = 0; nt < 5; nt++) {
        bf16x8 bk0 = *(const bf16x8*)&smem[KS_OFF + (nt * 16 + l15) * 72 + koff];
        bf16x8 bk1 = *(const bf16x8*)&smem[KS_OFF + (nt * 16 + l15) * 72 + 32 + koff];
        f32x4 c = {0.f, 0.f, 0.f, 0.f};
        c = __builtin_amdgcn_mfma_f32_16x16x32_bf16(aq0, bk0, c, 0, 0, 0);
        c = __builtin_amdgcn_mfma_f32_16x16x32_bf16(aq1, bk1, c, 0, 0, 0);
        #pragma unroll
        for (int r = 0; r < 4; r++) s[nt][r] = c[r];
    }
    // mask invalid n (only nt=4, l15>=13 -> n>=77)
    if (l15 >= N_ - 64) {
        #pragma unroll
        for (int r = 0; r < 4; r++) s[4][r] = -1e30f;
    }
    // ---- softmax over n (rows = quad*4+r within strip) ----
    float mx[4], li[4];
    #pragma unroll
    for (int r = 0; r < 4; r++) {
        float m = s[0][r];
        #pragma unroll
        for (int nt = 1; nt < 5; nt++) m = fmaxf(m, s[nt][r]);
        m = fmaxf(m, __shfl_xor(m, 1));
        m = fmaxf(m, __shfl_xor(m, 2));
        m = fmaxf(m, __shfl_xor(m, 4));
        m = fmaxf(m, __shfl_xor(m, 8));
        mx[r] = m;
        float l = 0.f;
        #pragma unroll
        for (int nt = 0; nt < 5; nt++) {
            float ev = __expf(s[nt][r] - m);
            s[nt][r] = ev;                      // reuse s[] for e
            l += ev;
        }
        l += __shfl_xor(l, 1);
        l += __shfl_xor(l, 2);
        l += __shfl_xor(l, 4);
        l += __shfl_xor(l, 8);
        li[r] = 1.f / l;
    }
    // write P (bf16) to LDS: row = w*16 + quad*4 + r, col = nt*16 + l15
    #pragma unroll
    for (int r = 0; r < 4; r++) {
        int prow = w * 16 + quad * 4 + r;
        #pragma unroll
        for (int nt = 0; nt < 5; nt++) {
            smem[PS_OFF + prow * 104 + nt * 16 + l15] = f2b(s[nt][r] * li[r]);
        }
    }
    // no barrier needed: this wave reads back only rows it wrote; per-wave
    // LDS ops are processed in order (compiler inserts lgkmcnt waits)

    // ---- PV ----
    bf16x8 pa0 = *(const bf16x8*)&smem[PS_OFF + mrow * 104 + 0  + koff];
    bf16x8 pa1 = *(const bf16x8*)&smem[PS_OFF + mrow * 104 + 32 + koff];
    bf16x8 pa2 = *(const bf16x8*)&smem[PS_OFF + mrow * 104 + 64 + koff];

    float* obase = qy + ((size_t)(b * T_ + t0 + w * 16)) * D_ + h * 64;
    #pragma unroll
    for (int dt = 0; dt < 4; dt++) {
        bf16x8 bv0 = *(const bf16x8*)&smem[VT_OFF + (dt * 16 + l15) * 104 + 0  + koff];
        bf16x8 bv1 = *(const bf16x8*)&smem[VT_OFF + (dt * 16 + l15) * 104 + 32 + koff];
        bf16x8 bv2 = *(const bf16x8*)&smem[VT_OFF + (dt * 16 + l15) * 104 + 64 + koff];
        f32x4 c = {0.f, 0.f, 0.f, 0.f};
        c = __builtin_amdgcn_mfma_f32_16x16x32_bf16(pa0, bv0, c, 0, 0, 0);
        c = __builtin_amdgcn_mfma_f32_16x16x32_bf16(pa1, bv1, c, 0, 0, 0);
        c = __builtin_amdgcn_mfma_f32_16x16x32_bf16(pa2, bv2, c, 0, 0, 0);
        #pragma unroll
        for (int r = 0; r < 4; r++) {
            obase[(size_t)(quad * 4 + r) * D_ + dt * 16 + l15] = c[r];
        }
    }
}

// ---------------------------------------------------------------------------
// e = silu(emb) @ emb_w.T + emb_b   -> [B, 2D]. One wave per output.
// ---------------------------------------------------------------------------
__global__ __launch_bounds__(256) void emb_proj_kernel(
    const float* __restrict__ emb, const float* __restrict__ emb_w,
    const float* __restrict__ emb_b, float* __restrict__ e)
{
    int wid = blockIdx.x * 4 + (threadIdx.x >> 6);
    int lane = threadIdx.x & 63;
    if (wid >= B_ * 2 * D_) return;
    int b = wid >> 10;
    int oo = wid & 1023;
    const float* wr = emb_w + (size_t)oo * TE_;
    const float* er = emb + (size_t)b * TE_;
    float acc = 0.f;
    for (int i = lane; i < TE_; i += 64) {
        float x = er[i];
        float sx = x * sigmoidf_fast(x);
        acc = fmaf(sx, wr[i], acc);
    }
    #pragma unroll
    for (int off = 32; off; off >>= 1) acc += __shfl_xor(acc, off);
    if (lane == 0) e[wid] = acc + emb_b[oo];
}

// ---------------------------------------------------------------------------
extern "C" void kernel_launch(void* const* d_in, const int* in_sizes, int n_in,
                              void* d_out, int out_size, void* d_ws, size_t ws_size,
                              hipStream_t stream)
{
    const float* x       = (const float*)d_in[0];
    const float* xf      = (const float*)d_in[1];
    const float* emb     = (const float*)d_in[2];
    const int*   cond    = (const int*)d_in[4];
    const float* norm_w  = (const float*)d_in[5];
    const float* norm_b  = (const float*)d_in[6];
    const float* tnorm_w = (const float*)d_in[7];
    const float* tnorm_b = (const float*)d_in[8];
    const float* Wq      = (const float*)d_in[9];
    const float* bq      = (const float*)d_in[10];
    const float* Wk      = (const float*)d_in[11];
    const float* bk      = (const float*)d_in[12];
    const float* Wv      = (const float*)d_in[13];
    const float* bv      = (const float*)d_in[14];
    const float* emb_w   = (const float*)d_in[15];
    const float* emb_b   = (const float*)d_in[16];
    const float* snorm_w = (const float*)d_in[17];
    const float* snorm_b = (const float*)d_in[18];
    const float* Wout    = (const float*)d_in[19];
    const float* bout    = (const float*)d_in[20];
    float* out = (float*)d_out;

    float* ws = (float*)d_ws;
    const size_t QY    = 0;                                  // 32768*512
    const size_t XFN   = QY    + (size_t)B_ * T_ * D_;       // 2464*256
    const size_t KBUF  = XFN   + (size_t)B_ * N_ * TD_;      // 2464*512
    const size_t VBUF  = KBUF  + (size_t)B_ * N_ * D_;       // 2464*512
    const size_t EBUF  = VBUF  + (size_t)B_ * N_ * D_;       // 32*1024
    const size_t XMU   = EBUF  + (size_t)B_ * 2 * D_;        // 32768
    const size_t XRS   = XMU   + (size_t)B_ * T_;
    const size_t YMU   = XRS   + (size_t)B_ * T_;
    const size_t YRS   = YMU   + (size_t)B_ * T_;

    float* qy   = ws + QY;
    float* xfn  = ws + XFN;
    float* kbuf = ws + KBUF;
    float* vbuf = ws + VBUF;
    float* ebuf = ws + EBUF;
    float* xmu  = ws + XMU;
    float* xrs  = ws + XRS;
    float* ymu  = ws + YMU;
    float* yrs  = ws + YRS;

    const int BT = B_ * T_;      // 32768
    const int BN = B_ * N_;      // 2464

    // 1. x row stats (fused LN in Q-proj GEMM)
    row_stats_kernel<<<BT / 4, 256, 0, stream>>>(x, xmu, xrs, BT, D_);
    // 2. xf layernorm (materialized)
    ln_rows_kernel<<<(BN + 3) / 4, 256, 0, stream>>>(xf, tnorm_w, tnorm_b, xfn, BN, TD_);
    // 3a. K projection: kbuf = xfn @ Wk^T + bk
    {
        dim3 grid(D_ / 64, (BN + 63) / 64);
        gemm_kernel<2><<<grid, 256, 0, stream>>>(xfn, Wk, bk, nullptr, nullptr, nullptr, nullptr,
                                                 nullptr, nullptr, nullptr, kbuf, BN, D_, TD_);
    }
    // 3b. V projection: vbuf = (xfn @ Wv^T + bv) * tc
    {
        dim3 grid(D_ / 64, (BN + 63) / 64);
        gemm_kernel<3><<<grid, 256, 0, stream>>>(xfn, Wv, bv, nullptr, nullptr, nullptr, nullptr,
                                                 nullptr, nullptr, cond, vbuf, BN, D_, TD_);
    }
    // 4. Q projection: qy = LN(x) @ Wq^T + bq
    {
        dim3 grid(D_ / 64, BT / 64);
        gemm_kernel<0><<<grid, 256, 0, stream>>>(x, Wq, bq, xmu, xrs, norm_w, norm_b,
                                                 nullptr, nullptr, nullptr, qy, BT, D_, D_);
    }
    // 5. attention (in-place qy -> y), bf16 MFMA
    {
        dim3 grid(T_ / 64, H_, B_);
        attn_mfma_kernel<<<grid, 256, 0, stream>>>(kbuf, vbuf, qy);
    }
    // 6. e = silu(emb) @ emb_w^T + emb_b
    emb_proj_kernel<<<(B_ * 2 * D_) / 4, 256, 0, stream>>>(emb, emb_w, emb_b, ebuf);
    // 7. y row stats
    row_stats_kernel<<<BT / 4, 256, 0, stream>>>(qy, ymu, yrs, BT, D_);
    // 8. out = x + silu(LN(y)*(1+scale)+shift) @ Wout^T + bout
    {
        dim3 grid(D_ / 64, BT / 64);
        gemm_kernel<1><<<grid, 256, 0, stream>>>(qy, Wout, bout, ymu, yrs, snorm_w, snorm_b,
                                                 ebuf, x, nullptr, out, BT, D_, D_);
    }
}

// Round 4
// 398.241 us; speedup vs baseline: 5.0165x; 2.1224x over previous
//
#include <hip/hip_runtime.h>
#include <math.h>

#define B_   32
#define T_   1024
#define N_   77
#define D_   512
#define TD_  256
#define TE_  2048
#define H_   8
#define DH_  64

typedef short bf16x8 __attribute__((ext_vector_type(8)));
typedef float f32x4  __attribute__((ext_vector_type(4)));

__device__ __forceinline__ float sigmoidf_fast(float x) {
    return 1.0f / (1.0f + __expf(-x));
}

// float -> bf16 bits, round-to-nearest-even
__device__ __forceinline__ unsigned short f2b(float f) {
    unsigned int u = __float_as_uint(f);
    unsigned int r = u + 0x7FFFu + ((u >> 16) & 1u);
    return (unsigned short)(r >> 16);
}

// async global->LDS 16B (wave-uniform LDS base + lane*16 required)
#define GL16(g, l) __builtin_amdgcn_global_load_lds(                         \
    (const __attribute__((address_space(1))) unsigned int*)(g),              \
    (__attribute__((address_space(3))) unsigned int*)(l), 16, 0, 0)

// ---------------------------------------------------------------------------
// Full LN (materialized) for xf: one wave per row of length cols.
// ---------------------------------------------------------------------------
__global__ __launch_bounds__(256) void ln_rows_kernel(
    const float* __restrict__ x, const float* __restrict__ w, const float* __restrict__ b,
    float* __restrict__ out, int rows, int cols)
{
    int wave = blockIdx.x * 4 + (threadIdx.x >> 6);
    int lane = threadIdx.x & 63;
    if (wave >= rows) return;
    const float* row = x + (size_t)wave * cols;
    float s = 0.f, ss = 0.f;
    for (int c = lane; c < cols; c += 64) {
        float v = row[c];
        s += v; ss += v * v;
    }
    #pragma unroll
    for (int off = 32; off; off >>= 1) {
        s  += __shfl_xor(s, off);
        ss += __shfl_xor(ss, off);
    }
    float m = s / cols;
    float var = ss / cols - m * m;
    float r = rsqrtf(var + 1e-5f);
    float* orow = out + (size_t)wave * cols;
    for (int c = lane; c < cols; c += 64) {
        orow[c] = (row[c] - m) * r * w[c] + b[c];
    }
}

// ---------------------------------------------------------------------------
// fp32 tiled GEMM (kept for the small K/V projections only).
// MODE 2: A as-is.                                                    (K proj)
// MODE 3: A as-is; output scaled by tc[row/77].                       (V proj)
// ---------------------------------------------------------------------------
template <int MODE>
__global__ __launch_bounds__(256) void gemm_kernel(
    const float* __restrict__ A, const float* __restrict__ W,
    const float* __restrict__ bias,
    const int*   __restrict__ cond,   // (MODE 3 only)
    float* __restrict__ C,
    int M, int NN, int K)
{
    const int tx = threadIdx.x & 15;
    const int ty = threadIdx.x >> 4;
    const int m0 = blockIdx.y * 64;
    const int n0 = blockIdx.x * 64;

    __shared__ float As[16][68];
    __shared__ float Ws[16][68];

    float acc[4][4] = {};

    for (int k0 = 0; k0 < K; k0 += 16) {
        int kk = k0 + tx;
        #pragma unroll
        for (int p = 0; p < 4; p++) {
            int row = ty + p * 16;
            int m = m0 + row;
            int mc = m < M ? m : (M - 1);
            As[tx][row] = A[(size_t)mc * K + kk];
        }
        #pragma unroll
        for (int p = 0; p < 4; p++) {
            int nn = ty + p * 16;
            Ws[tx][nn] = W[(size_t)(n0 + nn) * K + kk];
        }
        __syncthreads();
        #pragma unroll
        for (int cc = 0; cc < 16; cc++) {
            float4 av = *(const float4*)&As[cc][ty * 4];
            float4 wv = *(const float4*)&Ws[cc][tx * 4];
            float a4[4] = {av.x, av.y, av.z, av.w};
            float w4[4] = {wv.x, wv.y, wv.z, wv.w};
            #pragma unroll
            for (int i = 0; i < 4; i++)
                #pragma unroll
                for (int j = 0; j < 4; j++)
                    acc[i][j] = fmaf(a4[i], w4[j], acc[i][j]);
        }
        __syncthreads();
    }

    #pragma unroll
    for (int i = 0; i < 4; i++) {
        int m = m0 + ty * 4 + i;
        if (m >= M) continue;
        float rowscale = 1.f;
        if (MODE == 3) {
            int b3 = m / N_;
            rowscale = ((cond[b3] % 10) > 0) ? 1.f : 0.f;
        }
        #pragma unroll
        for (int j = 0; j < 4; j++) {
            int n = n0 + tx * 4 + j;
            float o = acc[i][j] + bias[n];
            if (MODE == 3) o *= rowscale;
            C[(size_t)m * NN + n] = o;
        }
    }
}

// ---------------------------------------------------------------------------
// fp32 -> bf16 convert (weights). 8 elements/thread.
// ---------------------------------------------------------------------------
__global__ __launch_bounds__(256) void f32_to_bf16_kernel(
    const float* __restrict__ src, unsigned short* __restrict__ dst)
{
    int idx = (blockIdx.x * 256 + threadIdx.x) * 8;
    float4 v0 = *(const float4*)(src + idx);
    float4 v1 = *(const float4*)(src + idx + 4);
    ushort4 o0 = {f2b(v0.x), f2b(v0.y), f2b(v0.z), f2b(v0.w)};
    ushort4 o1 = {f2b(v1.x), f2b(v1.y), f2b(v1.z), f2b(v1.w)};
    *(ushort4*)(dst + idx)     = o0;
    *(ushort4*)(dst + idx + 4) = o1;
}

// ---------------------------------------------------------------------------
// prep_q: out_bf16 = bf16(LN(x; norm_w, norm_b)). One wave per 512-row.
// ---------------------------------------------------------------------------
__global__ __launch_bounds__(256) void prep_q_kernel(
    const float* __restrict__ x, const float* __restrict__ w, const float* __restrict__ b,
    unsigned short* __restrict__ outb)
{
    int row = blockIdx.x * 4 + (threadIdx.x >> 6);
    int lane = threadIdx.x & 63;
    const float* rp = x + (size_t)row * D_ + lane * 8;
    float4 v0 = *(const float4*)rp;
    float4 v1 = *(const float4*)(rp + 4);
    float s  = v0.x + v0.y + v0.z + v0.w + v1.x + v1.y + v1.z + v1.w;
    float ss = v0.x*v0.x + v0.y*v0.y + v0.z*v0.z + v0.w*v0.w
             + v1.x*v1.x + v1.y*v1.y + v1.z*v1.z + v1.w*v1.w;
    #pragma unroll
    for (int off = 32; off; off >>= 1) {
        s  += __shfl_xor(s, off);
        ss += __shfl_xor(ss, off);
    }
    float m = s * (1.f / D_);
    float r = rsqrtf(ss * (1.f / D_) - m * m + 1e-5f);
    float4 w0 = *(const float4*)(w + lane * 8);
    float4 w1 = *(const float4*)(w + lane * 8 + 4);
    float4 b0 = *(const float4*)(b + lane * 8);
    float4 b1 = *(const float4*)(b + lane * 8 + 4);
    ushort4 o0, o1;
    o0.x = f2b((v0.x - m) * r * w0.x + b0.x);
    o0.y = f2b((v0.y - m) * r * w0.y + b0.y);
    o0.z = f2b((v0.z - m) * r * w0.z + b0.z);
    o0.w = f2b((v0.w - m) * r * w0.w + b0.w);
    o1.x = f2b((v1.x - m) * r * w1.x + b1.x);
    o1.y = f2b((v1.y - m) * r * w1.y + b1.y);
    o1.z = f2b((v1.z - m) * r * w1.z + b1.z);
    o1.w = f2b((v1.w - m) * r * w1.w + b1.w);
    unsigned short* op = outb + (size_t)row * D_ + lane * 8;
    *(ushort4*)op       = o0;
    *(ushort4*)(op + 4) = o1;
}

// ---------------------------------------------------------------------------
// prep_h: out_bf16 = bf16( silu( LN(y; snorm)* (1+scale[b]) + shift[b] ) )
// ---------------------------------------------------------------------------
__global__ __launch_bounds__(256) void prep_h_kernel(
    const float* __restrict__ y, const float* __restrict__ w, const float* __restrict__ b,
    const float* __restrict__ e, unsigned short* __restrict__ outb)
{
    int row = blockIdx.x * 4 + (threadIdx.x >> 6);
    int lane = threadIdx.x & 63;
    int bb = row >> 10;
    const float* rp = y + (size_t)row * D_ + lane * 8;
    float4 v0 = *(const float4*)rp;
    float4 v1 = *(const float4*)(rp + 4);
    float s  = v0.x + v0.y + v0.z + v0.w + v1.x + v1.y + v1.z + v1.w;
    float ss = v0.x*v0.x + v0.y*v0.y + v0.z*v0.z + v0.w*v0.w
             + v1.x*v1.x + v1.y*v1.y + v1.z*v1.z + v1.w*v1.w;
    #pragma unroll
    for (int off = 32; off; off >>= 1) {
        s  += __shfl_xor(s, off);
        ss += __shfl_xor(ss, off);
    }
    float m = s * (1.f / D_);
    float r = rsqrtf(ss * (1.f / D_) - m * m + 1e-5f);
    float4 w0 = *(const float4*)(w + lane * 8);
    float4 w1 = *(const float4*)(w + lane * 8 + 4);
    float4 b0 = *(const float4*)(b + lane * 8);
    float4 b1 = *(const float4*)(b + lane * 8 + 4);
    const float* ep = e + (size_t)bb * 1024 + lane * 8;
    float4 sc0 = *(const float4*)ep;
    float4 sc1 = *(const float4*)(ep + 4);
    float4 sh0 = *(const float4*)(ep + 512);
    float4 sh1 = *(const float4*)(ep + 512 + 4);
    float hv[8];
    hv[0] = ((v0.x - m) * r * w0.x + b0.x) * (1.f + sc0.x) + sh0.x;
    hv[1] = ((v0.y - m) * r * w0.y + b0.y) * (1.f + sc0.y) + sh0.y;
    hv[2] = ((v0.z - m) * r * w0.z + b0.z) * (1.f + sc0.z) + sh0.z;
    hv[3] = ((v0.w - m) * r * w0.w + b0.w) * (1.f + sc0.w) + sh0.w;
    hv[4] = ((v1.x - m) * r * w1.x + b1.x) * (1.f + sc1.x) + sh1.x;
    hv[5] = ((v1.y - m) * r * w1.y + b1.y) * (1.f + sc1.y) + sh1.y;
    hv[6] = ((v1.z - m) * r * w1.z + b1.z) * (1.f + sc1.z) + sh1.z;
    hv[7] = ((v1.w - m) * r * w1.w + b1.w) * (1.f + sc1.w) + sh1.w;
    ushort4 o0, o1;
    o0.x = f2b(hv[0] * sigmoidf_fast(hv[0]));
    o0.y = f2b(hv[1] * sigmoidf_fast(hv[1]));
    o0.z = f2b(hv[2] * sigmoidf_fast(hv[2]));
    o0.w = f2b(hv[3] * sigmoidf_fast(hv[3]));
    o1.x = f2b(hv[4] * sigmoidf_fast(hv[4]));
    o1.y = f2b(hv[5] * sigmoidf_fast(hv[5]));
    o1.z = f2b(hv[6] * sigmoidf_fast(hv[6]));
    o1.w = f2b(hv[7] * sigmoidf_fast(hv[7]));
    unsigned short* op = outb + (size_t)row * D_ + lane * 8;
    *(ushort4*)op       = o0;
    *(ushort4*)(op + 4) = o1;
}

// ---------------------------------------------------------------------------
// bf16 MFMA GEMM (m97 structure): C[M,512] = Ab[M,512] @ Wb[512,512]^T + bias
// (+ resid). 128x128 tile, BK=32, global_load_lds width 16, 4 waves of 64x64.
// M = 32768, N = K = 512 fixed. RESID: add resid (out-proj residual).
// ---------------------------------------------------------------------------
template <int RESID>
__global__ __launch_bounds__(256) void gemm_bf16_kernel(
    const unsigned short* __restrict__ Ab,
    const unsigned short* __restrict__ Wb,
    const float* __restrict__ bias,
    const float* __restrict__ resid,
    float* __restrict__ C)
{
    constexpr int K = 512;
    __shared__ __align__(16) unsigned short As[128 * 32];
    __shared__ __align__(16) unsigned short Bs[128 * 32];

    const int tid  = threadIdx.x;
    const int m0   = blockIdx.y * 128;
    const int n0   = blockIdx.x * 128;
    const int lane = tid & 63;
    const int w    = tid >> 6;
    const int l15  = lane & 15;
    const int quad = lane >> 4;
    const int wm   = (w >> 1) * 64;
    const int wn   = (w & 1) * 64;

    const int row_a = tid >> 2;     // 0..63 (16B chunk layout: 4 chunks/row)
    const int col16 = tid & 3;

    f32x4 acc[4][4];
    #pragma unroll
    for (int i = 0; i < 4; i++)
        #pragma unroll
        for (int j = 0; j < 4; j++)
            acc[i][j] = (f32x4){0.f, 0.f, 0.f, 0.f};

    const char* gAbase = (const char*)Ab + ((size_t)(m0 + row_a) * K) * 2 + col16 * 16;
    const char* gBbase = (const char*)Wb + ((size_t)(n0 + row_a) * K) * 2 + col16 * 16;
    char* lA = (char*)As + tid * 16;
    char* lB = (char*)Bs + tid * 16;

    for (int k0 = 0; k0 < K; k0 += 32) {
        const char* gA = gAbase + k0 * 2;
        const char* gB = gBbase + k0 * 2;
        GL16(gA, lA);
        GL16(gA + (size_t)64 * K * 2, lA + 4096);
        GL16(gB, lB);
        GL16(gB + (size_t)64 * K * 2, lB + 4096);
        __syncthreads();

        bf16x8 af[4], bfr[4];
        #pragma unroll
        for (int i = 0; i < 4; i++)
            af[i] = *(const bf16x8*)&As[(wm + i * 16 + l15) * 32 + quad * 8];
        #pragma unroll
        for (int j = 0; j < 4; j++)
            bfr[j] = *(const bf16x8*)&Bs[(wn + j * 16 + l15) * 32 + quad * 8];
        #pragma unroll
        for (int i = 0; i < 4; i++)
            #pragma unroll
            for (int j = 0; j < 4; j++)
                acc[i][j] = __builtin_amdgcn_mfma_f32_16x16x32_bf16(af[i], bfr[j], acc[i][j], 0, 0, 0);
        __syncthreads();
    }

    #pragma unroll
    for (int i = 0; i < 4; i++) {
        int mbase = m0 + wm + i * 16 + quad * 4;
        #pragma unroll
        for (int j = 0; j < 4; j++) {
            int n = n0 + wn + j * 16 + l15;
            float bn = bias[n];
            #pragma unroll
            for (int r = 0; r < 4; r++) {
                size_t off = (size_t)(mbase + r) * 512 + n;
                float v = acc[i][j][r] + bn;
                if (RESID) v += resid[off];
                C[off] = v;
            }
        }
    }
}

// ---------------------------------------------------------------------------
// MFMA bf16 cross-attention (unchanged from R3 — verified correct).
// ---------------------------------------------------------------------------
#define QS_OFF 0          // [64][72] bf16
#define KS_OFF 4608       // [80][72] bf16
#define VT_OFF 10368      // [64][104] bf16 (V transposed: row=d, col=n)
#define PS_OFF 17024      // [64][104] bf16 (P: row=t, col=n)
#define SMEM_SH 23680

__global__ __launch_bounds__(256) void attn_mfma_kernel(
    const float* __restrict__ kbuf, const float* __restrict__ vbuf,
    float* __restrict__ qy)
{
    __shared__ __align__(16) unsigned short smem[SMEM_SH];

    const int tid = threadIdx.x;
    const int t0 = blockIdx.x * 64;
    const int h  = blockIdx.y;
    const int b  = blockIdx.z;

    const float* qbase = qy + ((size_t)(b * T_ + t0)) * D_ + h * 64;
    #pragma unroll
    for (int i = 0; i < 4; i++) {
        int idx = tid + i * 256;
        int row = idx >> 4, c4 = idx & 15;
        float4 v = *(const float4*)(qbase + (size_t)row * D_ + c4 * 4);
        ushort4 o;
        o.x = f2b(v.x); o.y = f2b(v.y); o.z = f2b(v.z); o.w = f2b(v.w);
        *(ushort4*)&smem[QS_OFF + row * 72 + c4 * 4] = o;
    }
    const float* kbase = kbuf + (size_t)(b * N_) * D_ + h * 64;
    #pragma unroll
    for (int i = 0; i < 5; i++) {
        int idx = tid + i * 256;
        if (idx < N_ * 16) {
            int row = idx >> 4, c4 = idx & 15;
            float4 v = *(const float4*)(kbase + (size_t)row * D_ + c4 * 4);
            ushort4 o;
            o.x = f2b(v.x); o.y = f2b(v.y); o.z = f2b(v.z); o.w = f2b(v.w);
            *(ushort4*)&smem[KS_OFF + row * 72 + c4 * 4] = o;
        }
    }
    if (tid < 48) {
        int row = N_ + tid / 16, c4 = tid & 15;
        ushort4 z = {0, 0, 0, 0};
        *(ushort4*)&smem[KS_OFF + row * 72 + c4 * 4] = z;
    }
    const float* vbase = vbuf + (size_t)(b * N_) * D_ + h * 64;
    #pragma unroll
    for (int i = 0; i < 5; i++) {
        int idx = tid + i * 256;
        if (idx < N_ * 16) {
            int n = idx >> 4, c4 = idx & 15;
            float4 v = *(const float4*)(vbase + (size_t)n * D_ + c4 * 4);
            smem[VT_OFF + (c4 * 4 + 0) * 104 + n] = f2b(v.x);
            smem[VT_OFF + (c4 * 4 + 1) * 104 + n] = f2b(v.y);
            smem[VT_OFF + (c4 * 4 + 2) * 104 + n] = f2b(v.z);
            smem[VT_OFF + (c4 * 4 + 3) * 104 + n] = f2b(v.w);
        }
    }
    #pragma unroll
    for (int i = 0; i < 5; i++) {
        int idx = tid + i * 256;
        if (idx < 64 * 19) {
            int d = idx / 19, n = N_ + idx % 19;
            smem[VT_OFF + d * 104 + n] = 0;
        }
    }
    #pragma unroll
    for (int i = 0; i < 4; i++) {
        int idx = tid + i * 256;
        int row = idx >> 4, col = 80 + (idx & 15);
        smem[PS_OFF + row * 104 + col] = 0;
    }
    __syncthreads();

    const int lane = tid & 63;
    const int w    = tid >> 6;
    const int l15  = lane & 15;
    const int quad = lane >> 4;
    const int koff = quad * 8;
    const int mrow = w * 16 + l15;

    bf16x8 aq0 = *(const bf16x8*)&smem[QS_OFF + mrow * 72 + koff];
    bf16x8 aq1 = *(const bf16x8*)&smem[QS_OFF + mrow * 72 + 32 + koff];

    float s[5][4];
    #pragma unroll
    for (int nt = 0; nt < 5; nt++) {
        bf16x8 bk0 = *(const bf16x8*)&smem[KS_OFF + (nt * 16 + l15) * 72 + koff];
        bf16x8 bk1 = *(const bf16x8*)&smem[KS_OFF + (nt * 16 + l15) * 72 + 32 + koff];
        f32x4 c = {0.f, 0.f, 0.f, 0.f};
        c = __builtin_amdgcn_mfma_f32_16x16x32_bf16(aq0, bk0, c, 0, 0, 0);
        c = __builtin_amdgcn_mfma_f32_16x16x32_bf16(aq1, bk1, c, 0, 0, 0);
        #pragma unroll
        for (int r = 0; r < 4; r++) s[nt][r] = c[r];
    }
    if (l15 >= N_ - 64) {
        #pragma unroll
        for (int r = 0; r < 4; r++) s[4][r] = -1e30f;
    }
    float li[4];
    #pragma unroll
    for (int r = 0; r < 4; r++) {
        float m = s[0][r];
        #pragma unroll
        for (int nt = 1; nt < 5; nt++) m = fmaxf(m, s[nt][r]);
        m = fmaxf(m, __shfl_xor(m, 1));
        m = fmaxf(m, __shfl_xor(m, 2));
        m = fmaxf(m, __shfl_xor(m, 4));
        m = fmaxf(m, __shfl_xor(m, 8));
        float l = 0.f;
        #pragma unroll
        for (int nt = 0; nt < 5; nt++) {
            float ev = __expf(s[nt][r] - m);
            s[nt][r] = ev;
            l += ev;
        }
        l += __shfl_xor(l, 1);
        l += __shfl_xor(l, 2);
        l += __shfl_xor(l, 4);
        l += __shfl_xor(l, 8);
        li[r] = 1.f / l;
    }
    #pragma unroll
    for (int r = 0; r < 4; r++) {
        int prow = w * 16 + quad * 4 + r;
        #pragma unroll
        for (int nt = 0; nt < 5; nt++) {
            smem[PS_OFF + prow * 104 + nt * 16 + l15] = f2b(s[nt][r] * li[r]);
        }
    }
    // within-wave LDS write->read: per-wave LDS ordering + compiler lgkmcnt

    bf16x8 pa0 = *(const bf16x8*)&smem[PS_OFF + mrow * 104 + 0  + koff];
    bf16x8 pa1 = *(const bf16x8*)&smem[PS_OFF + mrow * 104 + 32 + koff];
    bf16x8 pa2 = *(const bf16x8*)&smem[PS_OFF + mrow * 104 + 64 + koff];

    float* obase = qy + ((size_t)(b * T_ + t0 + w * 16)) * D_ + h * 64;
    #pragma unroll
    for (int dt = 0; dt < 4; dt++) {
        bf16x8 bv0 = *(const bf16x8*)&smem[VT_OFF + (dt * 16 + l15) * 104 + 0  + koff];
        bf16x8 bv1 = *(const bf16x8*)&smem[VT_OFF + (dt * 16 + l15) * 104 + 32 + koff];
        bf16x8 bv2 = *(const bf16x8*)&smem[VT_OFF + (dt * 16 + l15) * 104 + 64 + koff];
        f32x4 c = {0.f, 0.f, 0.f, 0.f};
        c = __builtin_amdgcn_mfma_f32_16x16x32_bf16(pa0, bv0, c, 0, 0, 0);
        c = __builtin_amdgcn_mfma_f32_16x16x32_bf16(pa1, bv1, c, 0, 0, 0);
        c = __builtin_amdgcn_mfma_f32_16x16x32_bf16(pa2, bv2, c, 0, 0, 0);
        #pragma unroll
        for (int r = 0; r < 4; r++) {
            obase[(size_t)(quad * 4 + r) * D_ + dt * 16 + l15] = c[r];
        }
    }
}

// ---------------------------------------------------------------------------
// e = silu(emb) @ emb_w.T + emb_b   -> [B, 2D]. One wave per output.
// ---------------------------------------------------------------------------
__global__ __launch_bounds__(256) void emb_proj_kernel(
    const float* __restrict__ emb, const float* __restrict__ emb_w,
    const float* __restrict__ emb_b, float* __restrict__ e)
{
    int wid = blockIdx.x * 4 + (threadIdx.x >> 6);
    int lane = threadIdx.x & 63;
    if (wid >= B_ * 2 * D_) return;
    int b = wid >> 10;
    int oo = wid & 1023;
    const float* wr = emb_w + (size_t)oo * TE_;
    const float* er = emb + (size_t)b * TE_;
    float acc = 0.f;
    for (int i = lane; i < TE_; i += 64) {
        float x = er[i];
        float sx = x * sigmoidf_fast(x);
        acc = fmaf(sx, wr[i], acc);
    }
    #pragma unroll
    for (int off = 32; off; off >>= 1) acc += __shfl_xor(acc, off);
    if (lane == 0) e[wid] = acc + emb_b[oo];
}

// ---------------------------------------------------------------------------
extern "C" void kernel_launch(void* const* d_in, const int* in_sizes, int n_in,
                              void* d_out, int out_size, void* d_ws, size_t ws_size,
                              hipStream_t stream)
{
    const float* x       = (const float*)d_in[0];
    const float* xf      = (const float*)d_in[1];
    const float* emb     = (const float*)d_in[2];
    const int*   cond    = (const int*)d_in[4];
    const float* norm_w  = (const float*)d_in[5];
    const float* norm_b  = (const float*)d_in[6];
    const float* tnorm_w = (const float*)d_in[7];
    const float* tnorm_b = (const float*)d_in[8];
    const float* Wq      = (const float*)d_in[9];
    const float* bq      = (const float*)d_in[10];
    const float* Wk      = (const float*)d_in[11];
    const float* bk      = (const float*)d_in[12];
    const float* Wv      = (const float*)d_in[13];
    const float* bv      = (const float*)d_in[14];
    const float* emb_w   = (const float*)d_in[15];
    const float* emb_b   = (const float*)d_in[16];
    const float* snorm_w = (const float*)d_in[17];
    const float* snorm_b = (const float*)d_in[18];
    const float* Wout    = (const float*)d_in[19];
    const float* bout    = (const float*)d_in[20];
    float* out = (float*)d_out;

    float* ws = (float*)d_ws;
    float* qy   = ws;                                  // 32768*512 f32
    float* xfn  = qy   + (size_t)B_ * T_ * D_;         // 2464*256 f32
    float* kbuf = xfn  + (size_t)B_ * N_ * TD_;        // 2464*512 f32
    float* vbuf = kbuf + (size_t)B_ * N_ * D_;         // 2464*512 f32
    float* ebuf = vbuf + (size_t)B_ * N_ * D_;         // 32*1024 f32
    unsigned short* abh = (unsigned short*)(ebuf + (size_t)B_ * 2 * D_); // 32768*512 bf16 (xn then h)
    unsigned short* wqb = abh + (size_t)B_ * T_ * D_;  // 512*512 bf16
    unsigned short* wob = wqb + (size_t)D_ * D_;       // 512*512 bf16

    const int BT = B_ * T_;      // 32768
    const int BN = B_ * N_;      // 2464

    // 1. xf layernorm (materialized)
    ln_rows_kernel<<<(BN + 3) / 4, 256, 0, stream>>>(xf, tnorm_w, tnorm_b, xfn, BN, TD_);
    // 2a. K projection: kbuf = xfn @ Wk^T + bk (fp32, small)
    {
        dim3 grid(D_ / 64, (BN + 63) / 64);
        gemm_kernel<2><<<grid, 256, 0, stream>>>(xfn, Wk, bk, nullptr, kbuf, BN, D_, TD_);
    }
    // 2b. V projection: vbuf = (xfn @ Wv^T + bv) * tc (fp32, small)
    {
        dim3 grid(D_ / 64, (BN + 63) / 64);
        gemm_kernel<3><<<grid, 256, 0, stream>>>(xfn, Wv, bv, cond, vbuf, BN, D_, TD_);
    }
    // 3. weight converts (512*512 = 262144 elems; 8/thread -> 128 blocks)
    f32_to_bf16_kernel<<<128, 256, 0, stream>>>(Wq, wqb);
    f32_to_bf16_kernel<<<128, 256, 0, stream>>>(Wout, wob);
    // 4. prep A for Q-GEMM: abh = bf16(LN(x))
    prep_q_kernel<<<BT / 4, 256, 0, stream>>>(x, norm_w, norm_b, abh);
    // 5. Q projection (bf16 MFMA): qy = abh @ wqb^T + bq
    {
        dim3 grid(D_ / 128, BT / 128);
        gemm_bf16_kernel<0><<<grid, 256, 0, stream>>>(abh, wqb, bq, nullptr, qy);
    }
    // 6. attention (in-place qy -> y)
    {
        dim3 grid(T_ / 64, H_, B_);
        attn_mfma_kernel<<<grid, 256, 0, stream>>>(kbuf, vbuf, qy);
    }
    // 7. e = silu(emb) @ emb_w^T + emb_b
    emb_proj_kernel<<<(B_ * 2 * D_) / 4, 256, 0, stream>>>(emb, emb_w, emb_b, ebuf);
    // 8. prep A for out-GEMM: abh = bf16(silu(LN(y)*(1+sc)+sh))  (reuses abh)
    prep_h_kernel<<<BT / 4, 256, 0, stream>>>(qy, snorm_w, snorm_b, ebuf, abh);
    // 9. out projection (bf16 MFMA): out = abh @ wob^T + bout + x
    {
        dim3 grid(D_ / 128, BT / 128);
        gemm_bf16_kernel<1><<<grid, 256, 0, stream>>>(abh, wob, bout, x, out);
    }
}

// Round 5
// 349.420 us; speedup vs baseline: 5.7174x; 1.1397x over previous
//
#include <hip/hip_runtime.h>
#include <math.h>

#define B_   32
#define T_   1024
#define N_   77
#define D_   512
#define TD_  256
#define TE_  2048
#define H_   8
#define DH_  64

typedef short bf16x8 __attribute__((ext_vector_type(8)));
typedef float f32x4  __attribute__((ext_vector_type(4)));

__device__ __forceinline__ float sigmoidf_fast(float x) {
    return 1.0f / (1.0f + __expf(-x));
}

// float -> bf16 bits, round-to-nearest-even
__device__ __forceinline__ unsigned short f2b(float f) {
    unsigned int u = __float_as_uint(f);
    unsigned int r = u + 0x7FFFu + ((u >> 16) & 1u);
    return (unsigned short)(r >> 16);
}

// async global->LDS 16B (wave-uniform LDS base + lane*16 required)
#define GL16(g, l) __builtin_amdgcn_global_load_lds(                         \
    (const __attribute__((address_space(1))) unsigned int*)(g),              \
    (__attribute__((address_space(3))) unsigned int*)(l), 16, 0, 0)

// ---------------------------------------------------------------------------
// Full LN (materialized) for xf: one wave per row of length cols.
// ---------------------------------------------------------------------------
__global__ __launch_bounds__(256) void ln_rows_kernel(
    const float* __restrict__ x, const float* __restrict__ w, const float* __restrict__ b,
    float* __restrict__ out, int rows, int cols)
{
    int wave = blockIdx.x * 4 + (threadIdx.x >> 6);
    int lane = threadIdx.x & 63;
    if (wave >= rows) return;
    const float* row = x + (size_t)wave * cols;
    float s = 0.f, ss = 0.f;
    for (int c = lane; c < cols; c += 64) {
        float v = row[c];
        s += v; ss += v * v;
    }
    #pragma unroll
    for (int off = 32; off; off >>= 1) {
        s  += __shfl_xor(s, off);
        ss += __shfl_xor(ss, off);
    }
    float m = s / cols;
    float var = ss / cols - m * m;
    float r = rsqrtf(var + 1e-5f);
    float* orow = out + (size_t)wave * cols;
    for (int c = lane; c < cols; c += 64) {
        orow[c] = (row[c] - m) * r * w[c] + b[c];
    }
}

// ---------------------------------------------------------------------------
// fp32 tiled GEMM (small K/V projections only).
// MODE 2: A as-is (K proj).  MODE 3: output scaled by tc[row/77] (V proj).
// ---------------------------------------------------------------------------
template <int MODE>
__global__ __launch_bounds__(256) void gemm_kernel(
    const float* __restrict__ A, const float* __restrict__ W,
    const float* __restrict__ bias,
    const int*   __restrict__ cond,
    float* __restrict__ C,
    int M, int NN, int K)
{
    const int tx = threadIdx.x & 15;
    const int ty = threadIdx.x >> 4;
    const int m0 = blockIdx.y * 64;
    const int n0 = blockIdx.x * 64;

    __shared__ float As[16][68];
    __shared__ float Ws[16][68];

    float acc[4][4] = {};

    for (int k0 = 0; k0 < K; k0 += 16) {
        int kk = k0 + tx;
        #pragma unroll
        for (int p = 0; p < 4; p++) {
            int row = ty + p * 16;
            int m = m0 + row;
            int mc = m < M ? m : (M - 1);
            As[tx][row] = A[(size_t)mc * K + kk];
        }
        #pragma unroll
        for (int p = 0; p < 4; p++) {
            int nn = ty + p * 16;
            Ws[tx][nn] = W[(size_t)(n0 + nn) * K + kk];
        }
        __syncthreads();
        #pragma unroll
        for (int cc = 0; cc < 16; cc++) {
            float4 av = *(const float4*)&As[cc][ty * 4];
            float4 wv = *(const float4*)&Ws[cc][tx * 4];
            float a4[4] = {av.x, av.y, av.z, av.w};
            float w4[4] = {wv.x, wv.y, wv.z, wv.w};
            #pragma unroll
            for (int i = 0; i < 4; i++)
                #pragma unroll
                for (int j = 0; j < 4; j++)
                    acc[i][j] = fmaf(a4[i], w4[j], acc[i][j]);
        }
        __syncthreads();
    }

    #pragma unroll
    for (int i = 0; i < 4; i++) {
        int m = m0 + ty * 4 + i;
        if (m >= M) continue;
        float rowscale = 1.f;
        if (MODE == 3) {
            int b3 = m / N_;
            rowscale = ((cond[b3] % 10) > 0) ? 1.f : 0.f;
        }
        #pragma unroll
        for (int j = 0; j < 4; j++) {
            int n = n0 + tx * 4 + j;
            float o = acc[i][j] + bias[n];
            if (MODE == 3) o *= rowscale;
            C[(size_t)m * NN + n] = o;
        }
    }
}

// ---------------------------------------------------------------------------
// fp32 -> bf16 convert (weights). 8 elements/thread.
// ---------------------------------------------------------------------------
__global__ __launch_bounds__(256) void f32_to_bf16_kernel(
    const float* __restrict__ src, unsigned short* __restrict__ dst)
{
    int idx = (blockIdx.x * 256 + threadIdx.x) * 8;
    float4 v0 = *(const float4*)(src + idx);
    float4 v1 = *(const float4*)(src + idx + 4);
    ushort4 o0 = {f2b(v0.x), f2b(v0.y), f2b(v0.z), f2b(v0.w)};
    ushort4 o1 = {f2b(v1.x), f2b(v1.y), f2b(v1.z), f2b(v1.w)};
    *(ushort4*)(dst + idx)     = o0;
    *(ushort4*)(dst + idx + 4) = o1;
}

// ---------------------------------------------------------------------------
// silu elementwise: dst = silu(src), 4 elems/thread. (emb precompute)
// ---------------------------------------------------------------------------
__global__ __launch_bounds__(256) void silu_kernel(
    const float* __restrict__ src, float* __restrict__ dst)
{
    int idx = (blockIdx.x * 256 + threadIdx.x) * 4;
    float4 v = *(const float4*)(src + idx);
    v.x = v.x * sigmoidf_fast(v.x);
    v.y = v.y * sigmoidf_fast(v.y);
    v.z = v.z * sigmoidf_fast(v.z);
    v.w = v.w * sigmoidf_fast(v.w);
    *(float4*)(dst + idx) = v;
}

// ---------------------------------------------------------------------------
// emb GEMM: e[32][1024] = se[32][2048] @ emb_w[1024][2048]^T   (no bias;
// emb_b folded into prep_h). One wave per 4b x 4n output tile; float4 loads,
// 64 FMA per 8 loads; full-wave shfl reduction.
// ---------------------------------------------------------------------------
__global__ __launch_bounds__(256) void emb_gemm_kernel(
    const float* __restrict__ se, const float* __restrict__ W,
    float* __restrict__ e)
{
    int wid = blockIdx.x * 4 + (threadIdx.x >> 6);   // 0..2047
    int lane = threadIdx.x & 63;
    int ngrp = wid >> 3;        // 0..255  (4 n each)
    int bgrp = wid & 7;         // 0..7    (4 b each)

    float acc[4][4] = {};
    #pragma unroll 2
    for (int it = 0; it < 8; it++) {
        int k = (it * 64 + lane) * 4;
        float4 sv[4], wv[4];
        #pragma unroll
        for (int bi = 0; bi < 4; bi++)
            sv[bi] = *(const float4*)&se[(size_t)(bgrp * 4 + bi) * TE_ + k];
        #pragma unroll
        for (int ni = 0; ni < 4; ni++)
            wv[ni] = *(const float4*)&W[(size_t)(ngrp * 4 + ni) * TE_ + k];
        #pragma unroll
        for (int bi = 0; bi < 4; bi++)
            #pragma unroll
            for (int ni = 0; ni < 4; ni++) {
                acc[bi][ni] = fmaf(sv[bi].x, wv[ni].x, acc[bi][ni]);
                acc[bi][ni] = fmaf(sv[bi].y, wv[ni].y, acc[bi][ni]);
                acc[bi][ni] = fmaf(sv[bi].z, wv[ni].z, acc[bi][ni]);
                acc[bi][ni] = fmaf(sv[bi].w, wv[ni].w, acc[bi][ni]);
            }
    }
    #pragma unroll
    for (int bi = 0; bi < 4; bi++)
        #pragma unroll
        for (int ni = 0; ni < 4; ni++) {
            float a = acc[bi][ni];
            #pragma unroll
            for (int off = 32; off; off >>= 1) a += __shfl_xor(a, off);
            if (lane == 0)
                e[(size_t)(bgrp * 4 + bi) * 1024 + ngrp * 4 + ni] = a;
        }
}

// ---------------------------------------------------------------------------
// prep_q: out_bf16 = bf16(LN(x; norm_w, norm_b)). One wave per 512-row.
// ---------------------------------------------------------------------------
__global__ __launch_bounds__(256) void prep_q_kernel(
    const float* __restrict__ x, const float* __restrict__ w, const float* __restrict__ b,
    unsigned short* __restrict__ outb)
{
    int row = blockIdx.x * 4 + (threadIdx.x >> 6);
    int lane = threadIdx.x & 63;
    const float* rp = x + (size_t)row * D_ + lane * 8;
    float4 v0 = *(const float4*)rp;
    float4 v1 = *(const float4*)(rp + 4);
    float s  = v0.x + v0.y + v0.z + v0.w + v1.x + v1.y + v1.z + v1.w;
    float ss = v0.x*v0.x + v0.y*v0.y + v0.z*v0.z + v0.w*v0.w
             + v1.x*v1.x + v1.y*v1.y + v1.z*v1.z + v1.w*v1.w;
    #pragma unroll
    for (int off = 32; off; off >>= 1) {
        s  += __shfl_xor(s, off);
        ss += __shfl_xor(ss, off);
    }
    float m = s * (1.f / D_);
    float r = rsqrtf(ss * (1.f / D_) - m * m + 1e-5f);
    float4 w0 = *(const float4*)(w + lane * 8);
    float4 w1 = *(const float4*)(w + lane * 8 + 4);
    float4 b0 = *(const float4*)(b + lane * 8);
    float4 b1 = *(const float4*)(b + lane * 8 + 4);
    ushort4 o0, o1;
    o0.x = f2b((v0.x - m) * r * w0.x + b0.x);
    o0.y = f2b((v0.y - m) * r * w0.y + b0.y);
    o0.z = f2b((v0.z - m) * r * w0.z + b0.z);
    o0.w = f2b((v0.w - m) * r * w0.w + b0.w);
    o1.x = f2b((v1.x - m) * r * w1.x + b1.x);
    o1.y = f2b((v1.y - m) * r * w1.y + b1.y);
    o1.z = f2b((v1.z - m) * r * w1.z + b1.z);
    o1.w = f2b((v1.w - m) * r * w1.w + b1.w);
    unsigned short* op = outb + (size_t)row * D_ + lane * 8;
    *(ushort4*)op       = o0;
    *(ushort4*)(op + 4) = o1;
}

// ---------------------------------------------------------------------------
// prep_h: out_bf16 = bf16( silu( LN(y)*(1+sc) + sh ) ), sc/sh = e + emb_b.
// ---------------------------------------------------------------------------
__global__ __launch_bounds__(256) void prep_h_kernel(
    const float* __restrict__ y, const float* __restrict__ w, const float* __restrict__ b,
    const float* __restrict__ e, const float* __restrict__ emb_b,
    unsigned short* __restrict__ outb)
{
    int row = blockIdx.x * 4 + (threadIdx.x >> 6);
    int lane = threadIdx.x & 63;
    int bb = row >> 10;
    const float* rp = y + (size_t)row * D_ + lane * 8;
    float4 v0 = *(const float4*)rp;
    float4 v1 = *(const float4*)(rp + 4);
    float s  = v0.x + v0.y + v0.z + v0.w + v1.x + v1.y + v1.z + v1.w;
    float ss = v0.x*v0.x + v0.y*v0.y + v0.z*v0.z + v0.w*v0.w
             + v1.x*v1.x + v1.y*v1.y + v1.z*v1.z + v1.w*v1.w;
    #pragma unroll
    for (int off = 32; off; off >>= 1) {
        s  += __shfl_xor(s, off);
        ss += __shfl_xor(ss, off);
    }
    float m = s * (1.f / D_);
    float r = rsqrtf(ss * (1.f / D_) - m * m + 1e-5f);
    float4 w0 = *(const float4*)(w + lane * 8);
    float4 w1 = *(const float4*)(w + lane * 8 + 4);
    float4 b0 = *(const float4*)(b + lane * 8);
    float4 b1 = *(const float4*)(b + lane * 8 + 4);
    const float* ep = e + (size_t)bb * 1024 + lane * 8;
    float4 sc0 = *(const float4*)ep;
    float4 sc1 = *(const float4*)(ep + 4);
    float4 sh0 = *(const float4*)(ep + 512);
    float4 sh1 = *(const float4*)(ep + 512 + 4);
    float4 eb0 = *(const float4*)(emb_b + lane * 8);
    float4 eb1 = *(const float4*)(emb_b + lane * 8 + 4);
    float4 fb0 = *(const float4*)(emb_b + 512 + lane * 8);
    float4 fb1 = *(const float4*)(emb_b + 512 + lane * 8 + 4);
    sc0.x += eb0.x; sc0.y += eb0.y; sc0.z += eb0.z; sc0.w += eb0.w;
    sc1.x += eb1.x; sc1.y += eb1.y; sc1.z += eb1.z; sc1.w += eb1.w;
    sh0.x += fb0.x; sh0.y += fb0.y; sh0.z += fb0.z; sh0.w += fb0.w;
    sh1.x += fb1.x; sh1.y += fb1.y; sh1.z += fb1.z; sh1.w += fb1.w;
    float hv[8];
    hv[0] = ((v0.x - m) * r * w0.x + b0.x) * (1.f + sc0.x) + sh0.x;
    hv[1] = ((v0.y - m) * r * w0.y + b0.y) * (1.f + sc0.y) + sh0.y;
    hv[2] = ((v0.z - m) * r * w0.z + b0.z) * (1.f + sc0.z) + sh0.z;
    hv[3] = ((v0.w - m) * r * w0.w + b0.w) * (1.f + sc0.w) + sh0.w;
    hv[4] = ((v1.x - m) * r * w1.x + b1.x) * (1.f + sc1.x) + sh1.x;
    hv[5] = ((v1.y - m) * r * w1.y + b1.y) * (1.f + sc1.y) + sh1.y;
    hv[6] = ((v1.z - m) * r * w1.z + b1.z) * (1.f + sc1.z) + sh1.z;
    hv[7] = ((v1.w - m) * r * w1.w + b1.w) * (1.f + sc1.w) + sh1.w;
    ushort4 o0, o1;
    o0.x = f2b(hv[0] * sigmoidf_fast(hv[0]));
    o0.y = f2b(hv[1] * sigmoidf_fast(hv[1]));
    o0.z = f2b(hv[2] * sigmoidf_fast(hv[2]));
    o0.w = f2b(hv[3] * sigmoidf_fast(hv[3]));
    o1.x = f2b(hv[4] * sigmoidf_fast(hv[4]));
    o1.y = f2b(hv[5] * sigmoidf_fast(hv[5]));
    o1.z = f2b(hv[6] * sigmoidf_fast(hv[6]));
    o1.w = f2b(hv[7] * sigmoidf_fast(hv[7]));
    unsigned short* op = outb + (size_t)row * D_ + lane * 8;
    *(ushort4*)op       = o0;
    *(ushort4*)(op + 4) = o1;
}

// ---------------------------------------------------------------------------
// bf16 MFMA GEMM (m97 structure): 128x128 tile, BK=32, global_load_lds x16.
// RESID: add resid.  OUTBF: write bf16 (ushort) instead of fp32.
// ---------------------------------------------------------------------------
template <int RESID, int OUTBF>
__global__ __launch_bounds__(256) void gemm_bf16_kernel(
    const unsigned short* __restrict__ Ab,
    const unsigned short* __restrict__ Wb,
    const float* __restrict__ bias,
    const float* __restrict__ resid,
    void* __restrict__ Cv)
{
    constexpr int K = 512;
    __shared__ __align__(16) unsigned short As[128 * 32];
    __shared__ __align__(16) unsigned short Bs[128 * 32];

    const int tid  = threadIdx.x;
    const int m0   = blockIdx.y * 128;
    const int n0   = blockIdx.x * 128;
    const int lane = tid & 63;
    const int w    = tid >> 6;
    const int l15  = lane & 15;
    const int quad = lane >> 4;
    const int wm   = (w >> 1) * 64;
    const int wn   = (w & 1) * 64;

    const int row_a = tid >> 2;
    const int col16 = tid & 3;

    f32x4 acc[4][4];
    #pragma unroll
    for (int i = 0; i < 4; i++)
        #pragma unroll
        for (int j = 0; j < 4; j++)
            acc[i][j] = (f32x4){0.f, 0.f, 0.f, 0.f};

    const char* gAbase = (const char*)Ab + ((size_t)(m0 + row_a) * K) * 2 + col16 * 16;
    const char* gBbase = (const char*)Wb + ((size_t)(n0 + row_a) * K) * 2 + col16 * 16;
    char* lA = (char*)As + tid * 16;
    char* lB = (char*)Bs + tid * 16;

    for (int k0 = 0; k0 < K; k0 += 32) {
        const char* gA = gAbase + k0 * 2;
        const char* gB = gBbase + k0 * 2;
        GL16(gA, lA);
        GL16(gA + (size_t)64 * K * 2, lA + 4096);
        GL16(gB, lB);
        GL16(gB + (size_t)64 * K * 2, lB + 4096);
        __syncthreads();

        bf16x8 af[4], bfr[4];
        #pragma unroll
        for (int i = 0; i < 4; i++)
            af[i] = *(const bf16x8*)&As[(wm + i * 16 + l15) * 32 + quad * 8];
        #pragma unroll
        for (int j = 0; j < 4; j++)
            bfr[j] = *(const bf16x8*)&Bs[(wn + j * 16 + l15) * 32 + quad * 8];
        #pragma unroll
        for (int i = 0; i < 4; i++)
            #pragma unroll
            for (int j = 0; j < 4; j++)
                acc[i][j] = __builtin_amdgcn_mfma_f32_16x16x32_bf16(af[i], bfr[j], acc[i][j], 0, 0, 0);
        __syncthreads();
    }

    float* C = (float*)Cv;
    unsigned short* Cb = (unsigned short*)Cv;
    #pragma unroll
    for (int i = 0; i < 4; i++) {
        int mbase = m0 + wm + i * 16 + quad * 4;
        #pragma unroll
        for (int j = 0; j < 4; j++) {
            int n = n0 + wn + j * 16 + l15;
            float bn = bias[n];
            #pragma unroll
            for (int r = 0; r < 4; r++) {
                size_t off = (size_t)(mbase + r) * 512 + n;
                float v = acc[i][j][r] + bn;
                if (RESID) v += resid[off];
                if (OUTBF) Cb[off] = f2b(v);
                else       C[off]  = v;
            }
        }
    }
}

// ---------------------------------------------------------------------------
// MFMA bf16 cross-attention. Reads q from bf16 qb, writes y fp32 to yout.
// ---------------------------------------------------------------------------
#define QS_OFF 0          // [64][72] bf16
#define KS_OFF 4608       // [80][72] bf16
#define VT_OFF 10368      // [64][104] bf16 (V transposed: row=d, col=n)
#define PS_OFF 17024      // [64][104] bf16 (P: row=t, col=n)
#define SMEM_SH 23680

__global__ __launch_bounds__(256) void attn_mfma_kernel(
    const unsigned short* __restrict__ qb,
    const float* __restrict__ kbuf, const float* __restrict__ vbuf,
    float* __restrict__ yout)
{
    __shared__ __align__(16) unsigned short smem[SMEM_SH];

    const int tid = threadIdx.x;
    const int t0 = blockIdx.x * 64;
    const int h  = blockIdx.y;
    const int b  = blockIdx.z;

    // ---- stage Q (64x64 bf16, direct copy) ----
    const unsigned short* qbase = qb + ((size_t)(b * T_ + t0)) * D_ + h * 64;
    #pragma unroll
    for (int i = 0; i < 2; i++) {
        int idx = tid + i * 256;               // 512 chunks of 8 ushorts
        int row = idx >> 3, c8 = idx & 7;
        bf16x8 v = *(const bf16x8*)(qbase + (size_t)row * D_ + c8 * 8);
        *(bf16x8*)&smem[QS_OFF + row * 72 + c8 * 8] = v;
    }
    // ---- stage K (77x64), zero rows 77..79 ----
    const float* kbase = kbuf + (size_t)(b * N_) * D_ + h * 64;
    #pragma unroll
    for (int i = 0; i < 5; i++) {
        int idx = tid + i * 256;
        if (idx < N_ * 16) {
            int row = idx >> 4, c4 = idx & 15;
            float4 v = *(const float4*)(kbase + (size_t)row * D_ + c4 * 4);
            ushort4 o;
            o.x = f2b(v.x); o.y = f2b(v.y); o.z = f2b(v.z); o.w = f2b(v.w);
            *(ushort4*)&smem[KS_OFF + row * 72 + c4 * 4] = o;
        }
    }
    if (tid < 48) {
        int row = N_ + tid / 16, c4 = tid & 15;
        ushort4 z = {0, 0, 0, 0};
        *(ushort4*)&smem[KS_OFF + row * 72 + c4 * 4] = z;
    }
    // ---- stage V transposed (VsT[d][n]), zero cols 77..95 ----
    const float* vbase = vbuf + (size_t)(b * N_) * D_ + h * 64;
    #pragma unroll
    for (int i = 0; i < 5; i++) {
        int idx = tid + i * 256;
        if (idx < N_ * 16) {
            int n = idx >> 4, c4 = idx & 15;
            float4 v = *(const float4*)(vbase + (size_t)n * D_ + c4 * 4);
            smem[VT_OFF + (c4 * 4 + 0) * 104 + n] = f2b(v.x);
            smem[VT_OFF + (c4 * 4 + 1) * 104 + n] = f2b(v.y);
            smem[VT_OFF + (c4 * 4 + 2) * 104 + n] = f2b(v.z);
            smem[VT_OFF + (c4 * 4 + 3) * 104 + n] = f2b(v.w);
        }
    }
    #pragma unroll
    for (int i = 0; i < 5; i++) {
        int idx = tid + i * 256;
        if (idx < 64 * 19) {
            int d = idx / 19, n = N_ + idx % 19;
            smem[VT_OFF + d * 104 + n] = 0;
        }
    }
    // ---- zero P pad cols 80..95 ----
    #pragma unroll
    for (int i = 0; i < 4; i++) {
        int idx = tid + i * 256;
        int row = idx >> 4, col = 80 + (idx & 15);
        smem[PS_OFF + row * 104 + col] = 0;
    }
    __syncthreads();

    const int lane = tid & 63;
    const int w    = tid >> 6;
    const int l15  = lane & 15;
    const int quad = lane >> 4;
    const int koff = quad * 8;
    const int mrow = w * 16 + l15;

    bf16x8 aq0 = *(const bf16x8*)&smem[QS_OFF + mrow * 72 + koff];
    bf16x8 aq1 = *(const bf16x8*)&smem[QS_OFF + mrow * 72 + 32 + koff];

    float s[5][4];
    #pragma unroll
    for (int nt = 0; nt < 5; nt++) {
        bf16x8 bk0 = *(const bf16x8*)&smem[KS_OFF + (nt * 16 + l15) * 72 + koff];
        bf16x8 bk1 = *(const bf16x8*)&smem[KS_OFF + (nt * 16 + l15) * 72 + 32 + koff];
        f32x4 c = {0.f, 0.f, 0.f, 0.f};
        c = __builtin_amdgcn_mfma_f32_16x16x32_bf16(aq0, bk0, c, 0, 0, 0);
        c = __builtin_amdgcn_mfma_f32_16x16x32_bf16(aq1, bk1, c, 0, 0, 0);
        #pragma unroll
        for (int r = 0; r < 4; r++) s[nt][r] = c[r];
    }
    if (l15 >= N_ - 64) {
        #pragma unroll
        for (int r = 0; r < 4; r++) s[4][r] = -1e30f;
    }
    float li[4];
    #pragma unroll
    for (int r = 0; r < 4; r++) {
        float m = s[0][r];
        #pragma unroll
        for (int nt = 1; nt < 5; nt++) m = fmaxf(m, s[nt][r]);
        m = fmaxf(m, __shfl_xor(m, 1));
        m = fmaxf(m, __shfl_xor(m, 2));
        m = fmaxf(m, __shfl_xor(m, 4));
        m = fmaxf(m, __shfl_xor(m, 8));
        float l = 0.f;
        #pragma unroll
        for (int nt = 0; nt < 5; nt++) {
            float ev = __expf(s[nt][r] - m);
            s[nt][r] = ev;
            l += ev;
        }
        l += __shfl_xor(l, 1);
        l += __shfl_xor(l, 2);
        l += __shfl_xor(l, 4);
        l += __shfl_xor(l, 8);
        li[r] = 1.f / l;
    }
    #pragma unroll
    for (int r = 0; r < 4; r++) {
        int prow = w * 16 + quad * 4 + r;
        #pragma unroll
        for (int nt = 0; nt < 5; nt++) {
            smem[PS_OFF + prow * 104 + nt * 16 + l15] = f2b(s[nt][r] * li[r]);
        }
    }
    // within-wave LDS write->read: per-wave LDS ordering + compiler lgkmcnt

    bf16x8 pa0 = *(const bf16x8*)&smem[PS_OFF + mrow * 104 + 0  + koff];
    bf16x8 pa1 = *(const bf16x8*)&smem[PS_OFF + mrow * 104 + 32 + koff];
    bf16x8 pa2 = *(const bf16x8*)&smem[PS_OFF + mrow * 104 + 64 + koff];

    float* obase = yout + ((size_t)(b * T_ + t0 + w * 16)) * D_ + h * 64;
    #pragma unroll
    for (int dt = 0; dt < 4; dt++) {
        bf16x8 bv0 = *(const bf16x8*)&smem[VT_OFF + (dt * 16 + l15) * 104 + 0  + koff];
        bf16x8 bv1 = *(const bf16x8*)&smem[VT_OFF + (dt * 16 + l15) * 104 + 32 + koff];
        bf16x8 bv2 = *(const bf16x8*)&smem[VT_OFF + (dt * 16 + l15) * 104 + 64 + koff];
        f32x4 c = {0.f, 0.f, 0.f, 0.f};
        c = __builtin_amdgcn_mfma_f32_16x16x32_bf16(pa0, bv0, c, 0, 0, 0);
        c = __builtin_amdgcn_mfma_f32_16x16x32_bf16(pa1, bv1, c, 0, 0, 0);
        c = __builtin_amdgcn_mfma_f32_16x16x32_bf16(pa2, bv2, c, 0, 0, 0);
        #pragma unroll
        for (int r = 0; r < 4; r++) {
            obase[(size_t)(quad * 4 + r) * D_ + dt * 16 + l15] = c[r];
        }
    }
}

// ---------------------------------------------------------------------------
extern "C" void kernel_launch(void* const* d_in, const int* in_sizes, int n_in,
                              void* d_out, int out_size, void* d_ws, size_t ws_size,
                              hipStream_t stream)
{
    const float* x       = (const float*)d_in[0];
    const float* xf      = (const float*)d_in[1];
    const float* emb     = (const float*)d_in[2];
    const int*   cond    = (const int*)d_in[4];
    const float* norm_w  = (const float*)d_in[5];
    const float* norm_b  = (const float*)d_in[6];
    const float* tnorm_w = (const float*)d_in[7];
    const float* tnorm_b = (const float*)d_in[8];
    const float* Wq      = (const float*)d_in[9];
    const float* bq      = (const float*)d_in[10];
    const float* Wk      = (const float*)d_in[11];
    const float* bk      = (const float*)d_in[12];
    const float* Wv      = (const float*)d_in[13];
    const float* bv      = (const float*)d_in[14];
    const float* emb_w   = (const float*)d_in[15];
    const float* emb_b   = (const float*)d_in[16];
    const float* snorm_w = (const float*)d_in[17];
    const float* snorm_b = (const float*)d_in[18];
    const float* Wout    = (const float*)d_in[19];
    const float* bout    = (const float*)d_in[20];
    float* out = (float*)d_out;

    float* ws = (float*)d_ws;
    float* qy   = ws;                                  // 32768*512 f32 (y)
    float* xfn  = qy   + (size_t)B_ * T_ * D_;         // 2464*256 f32
    float* kbuf = xfn  + (size_t)B_ * N_ * TD_;        // 2464*512 f32
    float* vbuf = kbuf + (size_t)B_ * N_ * D_;         // 2464*512 f32
    float* ebuf = vbuf + (size_t)B_ * N_ * D_;         // 32*1024 f32
    float* sebuf= ebuf + (size_t)B_ * 2 * D_;          // 32*2048 f32
    unsigned short* abh = (unsigned short*)(sebuf + (size_t)B_ * TE_); // 32768*512 bf16
    unsigned short* wqb = abh + (size_t)B_ * T_ * D_;  // 512*512 bf16
    unsigned short* wob = wqb + (size_t)D_ * D_;       // 512*512 bf16
    unsigned short* qb  = (unsigned short*)d_out;      // 32768*512 bf16 scratch in d_out
                                                       // (dead before final GEMM overwrites)

    const int BT = B_ * T_;      // 32768
    const int BN = B_ * N_;      // 2464

    // 1. xf layernorm (materialized)
    ln_rows_kernel<<<(BN + 3) / 4, 256, 0, stream>>>(xf, tnorm_w, tnorm_b, xfn, BN, TD_);
    // 2a. K projection (fp32, small)
    {
        dim3 grid(D_ / 64, (BN + 63) / 64);
        gemm_kernel<2><<<grid, 256, 0, stream>>>(xfn, Wk, bk, nullptr, kbuf, BN, D_, TD_);
    }
    // 2b. V projection (fp32, small, tc-gated)
    {
        dim3 grid(D_ / 64, (BN + 63) / 64);
        gemm_kernel<3><<<grid, 256, 0, stream>>>(xfn, Wv, bv, cond, vbuf, BN, D_, TD_);
    }
    // 3. weight converts
    f32_to_bf16_kernel<<<128, 256, 0, stream>>>(Wq, wqb);
    f32_to_bf16_kernel<<<128, 256, 0, stream>>>(Wout, wob);
    // 4. prep A for Q-GEMM: abh = bf16(LN(x))
    prep_q_kernel<<<BT / 4, 256, 0, stream>>>(x, norm_w, norm_b, abh);
    // 5. Q projection (bf16 MFMA, bf16 output): qb = bf16(abh @ wqb^T + bq)
    {
        dim3 grid(D_ / 128, BT / 128);
        gemm_bf16_kernel<0, 1><<<grid, 256, 0, stream>>>(abh, wqb, bq, nullptr, qb);
    }
    // 6. emb path: se = silu(emb); ebuf = se @ emb_w^T (bias folded into prep_h)
    silu_kernel<<<(B_ * TE_) / 1024, 256, 0, stream>>>(emb, sebuf);
    emb_gemm_kernel<<<512, 256, 0, stream>>>(sebuf, emb_w, ebuf);
    // 7. attention: qb (bf16) -> y (fp32, qy)
    {
        dim3 grid(T_ / 64, H_, B_);
        attn_mfma_kernel<<<grid, 256, 0, stream>>>(qb, kbuf, vbuf, qy);
    }
    // 8. prep A for out-GEMM: abh = bf16(silu(LN(y)*(1+sc)+sh))
    prep_h_kernel<<<BT / 4, 256, 0, stream>>>(qy, snorm_w, snorm_b, ebuf, emb_b, abh);
    // 9. out projection (bf16 MFMA, fp32 out + residual): out = abh @ wob^T + bout + x
    {
        dim3 grid(D_ / 128, BT / 128);
        gemm_bf16_kernel<1, 0><<<grid, 256, 0, stream>>>(abh, wob, bout, x, out);
    }
}